// Round 7
// baseline (157.858 us; speedup 1.0000x reference)
//
#include <hip/hip_runtime.h>
#include <utility>

#define NW 14
#define NL 3
#define DIM 16384            // 2^14
#define NG  (NL * NW)        // 42 fused RY*RX gates
#define TPB 1024
#define MAXSP 12

typedef float v2f __attribute__((ext_vector_type(2)));

// ---------------- schedule structures ----------------
struct SP {
    int J = 0, nr = 0, nl = 0;        // gates, reg-gates, lane-gates
    unsigned dirs[4]  = {};           // raw reg/filler coset dirs
    unsigned traw[10] = {};           // raw transversal dirs for tid bits 0..9
    unsigned tR[10] = {}, tW[10] = {};// sigma-adjusted transversal dirs (read/write)
    unsigned sxR[16] = {}, sxW[16] = {};
    unsigned pv[8]   = {};            // per-gate 10-bit tid-parity mask (runtime sign)
    unsigned cpar[8] = {};            // per-gate 16-bit per-amp compile-time sign
    unsigned gid[8]  = {};
    int wflag = 1;                    // has LDS write-back
};
struct Sched2 {
    int nsp = 0;
    SP sp[MAXSP] = {};
    unsigned stA[10] = {};            // sigma0-adjusted staging dirs (4<<b)
    unsigned stK[4]  = {};            // sigma0-adjusted (k<<12)
    unsigned pz[NW]  = {};            // measurement: tid parity mask per wire
    unsigned nib[NW] = {};            // measurement: 4-bit WHT bucket per wire
    int ok = 1;
};

// apply linear fold f (bits 4..13 -> bits 0..3) given 10 nibbles; returns x ^ f(x)
constexpr unsigned fap(const unsigned* g, unsigned x) {
    unsigned r = 0;
    for (int b = 4; b < 14; ++b) if ((x >> b) & 1u) r ^= g[b - 4];
    return x ^ r;
}
constexpr int rank4n(const unsigned* v) {   // rank of 4 nibbles
    unsigned bas[4] = {}; int nb = 0;
    for (int i = 0; i < 4; ++i) {
        unsigned r = v[i] & 15u;
        for (int j = 0; j < nb; ++j) {
            int hb = 3; while (hb > 0 && !((bas[j] >> hb) & 1u)) --hb;
            if ((r >> hb) & 1u) r ^= bas[j];
        }
        if (r) bas[nb++] = r;
    }
    return nb;
}

constexpr Sched2 build2() {
    Sched2 S{};
    unsigned mk[NG] = {}, vmg[NG] = {}, zm[NW] = {};
    {   // per-gate pair masks (M^-1 columns) and value masks (frame rows)
        unsigned A[NW] = {};
        for (int w = 0; w < NW; ++w) A[w] = 1u << (NW - 1 - w);
        int g = 0;
        for (int l = 0; l < NL; ++l) {
            unsigned rows[NW] = {};
            for (int u = 0; u < NW; ++u) rows[u] = A[u] | (1u << (NW + u));
            for (int col = 0; col < NW; ++col) {
                int piv = col;
                while (piv < NW && !((rows[piv] >> col) & 1u)) ++piv;
                if (piv >= NW) { S.ok = 0; continue; }
                unsigned tmp = rows[col]; rows[col] = rows[piv]; rows[piv] = tmp;
                for (int r = 0; r < NW; ++r)
                    if (r != col && ((rows[r] >> col) & 1u)) rows[r] ^= rows[col];
            }
            for (int w = 0; w < NW; ++w) {
                unsigned m = 0;
                for (int r = 0; r < NW; ++r) m |= ((rows[r] >> (NW + w)) & 1u) << r;
                mk[g] = m; vmg[g] = A[w]; ++g;
            }
            for (int w = 0; w < NW - 1; ++w) A[w + 1] ^= A[w];  // virtual CNOT chain
            A[0] ^= A[NW - 1];
        }
        for (int w = 0; w < NW; ++w) zm[w] = A[w];
    }
    // ---- greedy grouping into superphases of <=8 independent masks
    int gs = 0;
    while (gs < NG && S.nsp < MAXSP) {
        SP& P = S.sp[S.nsp];
        unsigned bas[14] = {}; int nb = 0;
        int j = gs;
        while (j < NG && (j - gs) < 8) {
            unsigned r = mk[j];
            for (int i = 0; i < nb; ++i) {
                int hb = 13; while (hb > 0 && !((bas[i] >> hb) & 1u)) --hb;
                if ((r >> hb) & 1u) r ^= bas[i];
            }
            if (!r) break;
            bas[nb++] = r; ++j;
        }
        P.J = j - gs; P.nr = P.J < 4 ? P.J : 4; P.nl = P.J - P.nr;
        for (int q = 0; q < P.J; ++q) P.gid[q] = (unsigned)(gs + q);
        for (int q = 0; q < P.nr; ++q) P.dirs[q] = mk[gs + q];
        // fillers for reg dirs (units independent of group span)
        for (int q = P.nr; q < 4; ++q) {
            for (int b = 0; b < NW; ++b) {
                unsigned r = 1u << b;
                for (int i = 0; i < nb; ++i) {
                    int hb = 13; while (hb > 0 && !((bas[i] >> hb) & 1u)) --hb;
                    if ((r >> hb) & 1u) r ^= bas[i];
                }
                if (r) { bas[nb++] = r; P.dirs[q] = 1u << b; break; }
            }
        }
        // lane transversal dirs (triangular solve for patterns 1,2,7,15)
        unsigned lm[4] = {};
        for (int i = 0; i < P.nl; ++i) lm[i] = mk[gs + 4 + i];
        unsigned tt[4] = { 0, 0, 0, 0 };
        if (P.nl > 0) tt[0] = lm[0];
        if (P.nl > 1) tt[1] = lm[1];
        if (P.nl > 2) tt[2] = lm[2] ^ tt[0] ^ tt[1];
        if (P.nl > 3) tt[3] = lm[3] ^ lm[2];
        for (int i = P.nl; i < 4; ++i) {   // filler lane dirs
            for (int b = 0; b < NW; ++b) {
                unsigned r = 1u << b;
                for (int k2 = 0; k2 < nb; ++k2) {
                    int hb = 13; while (hb > 0 && !((bas[k2] >> hb) & 1u)) --hb;
                    if ((r >> hb) & 1u) r ^= bas[k2];
                }
                if (r) { bas[nb++] = r; tt[i] = 1u << b; break; }
            }
        }
        for (int i = 0; i < 4; ++i) P.traw[i] = tt[i];
        // wave transversal dirs t4..t9 (units completing the basis)
        for (int b6 = 4; b6 < 10; ++b6) {
            for (int b = 0; b < NW; ++b) {
                unsigned r = 1u << b;
                for (int k2 = 0; k2 < nb; ++k2) {
                    int hb = 13; while (hb > 0 && !((bas[k2] >> hb) & 1u)) --hb;
                    if ((r >> hb) & 1u) r ^= bas[k2];
                }
                if (r) { bas[nb++] = r; P.traw[b6] = 1u << b; break; }
            }
        }
        if (nb != 14) S.ok = 0;
        // signs
        for (int q = 0; q < P.J; ++q) {
            unsigned vm = vmg[gs + q], p = 0;
            for (int b = 0; b < 10; ++b)
                if (__builtin_popcount(P.traw[b] & vm) & 1) p |= 1u << b;
            P.pv[q] = p;
            unsigned cp = 0;
            for (int s = 0; s < 16; ++s) {
                unsigned sx = 0;
                for (int q2 = 0; q2 < 4; ++q2) if ((s >> q2) & 1) sx ^= P.dirs[q2];
                if (__builtin_popcount(sx & vm) & 1) cp |= 1u << s;
            }
            P.cpar[q] = cp;
        }
        ++S.nsp; gs = j;
    }
    if (gs < NG) S.ok = 0;
    S.sp[S.nsp - 1].wflag = 0;
    // ---- per-transition swizzle search (write dirs of t-1 / stage, read dirs of t)
    for (int t = 0; t < S.nsp; ++t) {
        unsigned wd[4] = {}, rd[4] = {};
        if (t == 0) { wd[0] = 4; wd[1] = 8; wd[2] = 16; wd[3] = 32; }
        else for (int i = 0; i < 4; ++i) wd[i] = S.sp[t - 1].traw[i];
        for (int i = 0; i < 4; ++i) rd[i] = S.sp[t].traw[i];
        unsigned bg[10] = {}; int bscore = -1;
        for (unsigned seed = 0; seed < 512u; ++seed) {
            unsigned g[10] = {};
            if (seed) {
                for (int b = 0; b < 10; ++b) {
                    unsigned h = (seed * 2654435761u) ^ ((unsigned)(b + 3) * 0x9E3779B9u);
                    h ^= h >> 16; h *= 2246822519u; h ^= h >> 13;
                    g[b] = h & 15u;
                }
            }
            unsigned W[4] = {}, R[4] = {};
            for (int i = 0; i < 4; ++i) { W[i] = fap(g, wd[i]); R[i] = fap(g, rd[i]); }
            int sc = rank4n(W) + rank4n(R);
            if (sc > bscore) {
                bscore = sc;
                for (int b = 0; b < 10; ++b) bg[b] = g[b];
                if (sc == 8) break;
            }
        }
        for (int b = 0; b < 10; ++b) S.sp[t].tR[b] = fap(bg, S.sp[t].traw[b]);
        for (int s = 0; s < 16; ++s) {
            unsigned sx = 0;
            for (int q = 0; q < 4; ++q) if ((s >> q) & 1) sx ^= S.sp[t].dirs[q];
            S.sp[t].sxR[s] = fap(bg, sx);
        }
        if (t == 0) {
            for (int b = 0; b < 10; ++b) S.stA[b] = fap(bg, 4u << b);
            for (int k = 0; k < 4; ++k) S.stK[k] = fap(bg, (unsigned)k << 12);
        } else {
            for (int b = 0; b < 10; ++b) S.sp[t - 1].tW[b] = fap(bg, S.sp[t - 1].traw[b]);
            for (int s = 0; s < 16; ++s) {
                unsigned sx = 0;
                for (int q = 0; q < 4; ++q) if ((s >> q) & 1) sx ^= S.sp[t - 1].dirs[q];
                S.sp[t - 1].sxW[s] = fap(bg, sx);
            }
        }
    }
    // ---- measurement from last SP's register frame
    for (int w = 0; w < NW; ++w) {
        const SP& L = S.sp[S.nsp - 1];
        unsigned p = 0;
        for (int b = 0; b < 10; ++b)
            if (__builtin_popcount(L.traw[b] & zm[w]) & 1) p |= 1u << b;
        S.pz[w] = p;
        unsigned nv = 0;
        for (int q = 0; q < 4; ++q)
            if (__builtin_popcount(L.dirs[q] & zm[w]) & 1) nv |= 1u << q;
        S.nib[w] = nv;
    }
    return S;
}
constexpr Sched2 SC2 = build2();
static_assert(SC2.ok == 1, "schedule build failed");
static_assert(SC2.nsp <= MAXSP, "too many superphases");

// ---------------- static_for ----------------
template<class F, unsigned... I>
__device__ __forceinline__ void static_for_impl(F&& f, std::integer_sequence<unsigned, I...>) {
    (f(std::integral_constant<unsigned, I>{}), ...);
}
template<unsigned N, class F>
__device__ __forceinline__ void static_for(F&& f) {
    static_for_impl(static_cast<F&&>(f), std::make_integer_sequence<unsigned, N>{});
}

// ---------------- packed complex mul/mac (verified r4/r6) ----------------
template<int NEGLO, int NEGHI>
__device__ __forceinline__ v2f cmul(v2f k, v2f x) {
    v2f y;
    if constexpr (!NEGLO)
        asm("v_pk_mul_f32 %0, %1, %2 op_sel:[0,0] op_sel_hi:[0,1]"
            : "=&v"(y) : "v"(k), "v"(x));
    else
        asm("v_pk_mul_f32 %0, %1, %2 op_sel:[0,0] op_sel_hi:[0,1] neg_lo:[1,0] neg_hi:[1,0]"
            : "=&v"(y) : "v"(k), "v"(x));
    if constexpr (!NEGHI)
        asm("v_pk_fma_f32 %0, %1, %2, %0 op_sel:[1,1,0] op_sel_hi:[1,0,1] neg_lo:[0,1,0]"
            : "+v"(y) : "v"(k), "v"(x));
    else
        asm("v_pk_fma_f32 %0, %1, %2, %0 op_sel:[1,1,0] op_sel_hi:[1,0,1] neg_lo:[1,1,0] neg_hi:[1,0,0]"
            : "+v"(y) : "v"(k), "v"(x));
    return y;
}
template<int NEGLO, int NEGHI>
__device__ __forceinline__ void cmac(v2f& y, v2f k, v2f x) {
    if constexpr (!NEGLO)
        asm("v_pk_fma_f32 %0, %1, %2, %0 op_sel:[0,0,0] op_sel_hi:[0,1,1]"
            : "+v"(y) : "v"(k), "v"(x));
    else
        asm("v_pk_fma_f32 %0, %1, %2, %0 op_sel:[0,0,0] op_sel_hi:[0,1,1] neg_lo:[1,0,0] neg_hi:[1,0,0]"
            : "+v"(y) : "v"(k), "v"(x));
    if constexpr (!NEGHI)
        asm("v_pk_fma_f32 %0, %1, %2, %0 op_sel:[1,1,0] op_sel_hi:[1,0,1] neg_lo:[0,1,0]"
            : "+v"(y) : "v"(k), "v"(x));
    else
        asm("v_pk_fma_f32 %0, %1, %2, %0 op_sel:[1,1,0] op_sel_hi:[1,0,1] neg_lo:[1,1,0] neg_hi:[1,0,0]"
            : "+v"(y) : "v"(k), "v"(x));
}
// unified per-amp forms: y = (ar, +-ai)*own [+ ((+-br), bi)*recv]
template<bool CS> __device__ __forceinline__ v2f  cmulA(v2f k, v2f x) { return cmul<0, CS ? 1 : 0>(k, x); }
template<bool CS> __device__ __forceinline__ void cmacB(v2f& y, v2f k, v2f x) { cmac<CS ? 1 : 0, 0>(y, k, x); }

// ---------------- DPP lane exchange ----------------
constexpr int lane_ctrl(int li) {   // patterns xor1, xor2, xor7, xor15
    return li == 0 ? 0xB1 : li == 1 ? 0x4E : li == 2 ? 0x141 : 0x140;
}
template<int CTRL>
__device__ __forceinline__ v2f dppx(v2f x) {
    int lo = __builtin_amdgcn_update_dpp(0, __float_as_int(x.x), CTRL, 0xf, 0xf, false);
    int hi = __builtin_amdgcn_update_dpp(0, __float_as_int(x.y), CTRL, 0xf, 0xf, false);
    return (v2f){ __int_as_float(lo), __int_as_float(hi) };
}

// ---------------- one superphase ----------------
template<int PIDX>
__device__ __forceinline__ void apply_sp(char* psiB, const float4* __restrict__ umat,
                                         unsigned tid, v2f* x)
{
    // fold read+write reps together (packed 16+16 bits)
    unsigned frep = 0;
    static_for<10>([&](auto Bc) {
        constexpr int b = (int)decltype(Bc)::value;
        constexpr unsigned mm = SC2.sp[PIDX].tR[b] |
                                (SC2.sp[PIDX].wflag ? (SC2.sp[PIDX].tW[b] << 16) : 0u);
        frep ^= mm & (unsigned)(-(int)((tid >> b) & 1u));
    });
    const unsigned srepR8 = (frep & 0x3FFFu) << 3;
    const unsigned srepW8 = ((frep >> 16) & 0x3FFFu) << 3;

    static_for<16>([&](auto Sc) {
        constexpr unsigned s = decltype(Sc)::value;
        constexpr unsigned off = SC2.sp[PIDX].sxR[s] << 3;
        x[s] = *(const v2f*)(psiB + (srepR8 ^ off));
    });
    if constexpr (SC2.sp[PIDX].wflag)
        __syncthreads();   // all reads done before anyone writes the new frame

    static_for<8>([&](auto Qc) {
        constexpr int q = (int)decltype(Qc)::value;
        if constexpr (q < SC2.sp[PIDX].J) {
            constexpr unsigned cp = SC2.sp[PIDX].cpar[q];
            constexpr unsigned pv = SC2.sp[PIDX].pv[q];
            const float4 u = umat[SC2.sp[PIDX].gid[q]];
            const unsigned sm = ((unsigned)__popc(tid & pv)) << 31;
            v2f A, B;  // A = (ar, ai^s), B = (br^s, bi)
            A.x = u.x; A.y = __uint_as_float(__float_as_uint(u.y) ^ sm);
            B.x = __uint_as_float(__float_as_uint(u.z) ^ sm); B.y = u.w;
            if constexpr (q < SC2.sp[PIDX].nr) {
                static_for<8>([&](auto Pc) {
                    constexpr unsigned p    = decltype(Pc)::value;
                    constexpr unsigned lowm = (1u << q) - 1u;
                    constexpr unsigned s0   = ((p & ~lowm) << 1) | (p & lowm);
                    constexpr unsigned s1   = s0 | (1u << q);
                    constexpr bool c0 = (cp >> s0) & 1u;
                    constexpr bool c1 = (cp >> s1) & 1u;
                    const v2f x0 = x[s0], x1 = x[s1];
                    v2f y0 = cmulA<c0>(A, x0); cmacB<c0>(y0, B, x1);
                    v2f y1 = cmulA<c1>(A, x1); cmacB<c1>(y1, B, x0);
                    x[s0] = y0; x[s1] = y1;
                });
            } else {
                constexpr int ctrl = lane_ctrl(q - SC2.sp[PIDX].nr);
                static_for<16>([&](auto Sc) {
                    constexpr unsigned s = decltype(Sc)::value;
                    constexpr bool cs = (cp >> s) & 1u;
                    v2f recv = dppx<ctrl>(x[s]);
                    v2f y = cmulA<cs>(A, x[s]); cmacB<cs>(y, B, recv);
                    x[s] = y;
                });
            }
        }
    });

    if constexpr (SC2.sp[PIDX].wflag) {
        static_for<16>([&](auto Sc) {
            constexpr unsigned s = decltype(Sc)::value;
            constexpr unsigned off = SC2.sp[PIDX].sxW[s] << 3;
            *(v2f*)(psiB + (srepW8 ^ off)) = x[s];
        });
        __syncthreads();   // new frame visible before next SP reads
    }
}

__global__ __launch_bounds__(TPB) void qsim_kernel(
    const float* __restrict__ state,
    const float* __restrict__ params,
    const float* __restrict__ head_w,
    const float* __restrict__ head_b,
    float* __restrict__ out)
{
    __shared__ v2f    psi[DIM];          // 128 KB
    __shared__ float4 umat[NG];
    __shared__ float  red[TPB / 64];
    char* psiB = (char*)psi;
    const unsigned tid = threadIdx.x;

    // Fused U = RY(t2)*RX(t1) = [[a,b],[-conj(b),conj(a)]]; a=(c1c2,s1s2), b=(-s2c1,-c2s1)
    if (tid < NG) {
        float t1 = 0.5f * params[2 * tid + 0];
        float t2 = 0.5f * params[2 * tid + 1];
        float s1, c1, s2, c2;
        sincosf(t1, &s1, &c1);
        sincosf(t2, &s2, &c2);
        umat[tid] = make_float4(c1 * c2, s1 * s2, -s2 * c1, -c2 * s1);
    }

    // Stage: coalesced global float4 -> sigma0-swizzled LDS (imag = 0)
    unsigned tpart = 0;
    static_for<10>([&](auto Bc) {
        constexpr int b = (int)decltype(Bc)::value;
        constexpr unsigned m = SC2.stA[b];
        tpart ^= m & (unsigned)(-(int)((tid >> b) & 1u));
    });
    const float4* st4 = reinterpret_cast<const float4*>(state) + (size_t)blockIdx.x * (DIM / 4);
    static_for<4>([&](auto Kc) {
        constexpr int k = (int)decltype(Kc)::value;
        float4 v = st4[tid + k * TPB];
        const unsigned bb = (tpart ^ SC2.stK[k]) << 3;
        *(v2f*)(psiB + (bb ^ (0u << 3))) = (v2f){ v.x, 0.f };
        *(v2f*)(psiB + (bb ^ (1u << 3))) = (v2f){ v.y, 0.f };
        *(v2f*)(psiB + (bb ^ (2u << 3))) = (v2f){ v.z, 0.f };
        *(v2f*)(psiB + (bb ^ (3u << 3))) = (v2f){ v.w, 0.f };
    });
    __syncthreads();

    v2f x[16];
    static_for<MAXSP>([&](auto Pc) {
        constexpr int p = (int)decltype(Pc)::value;
        if constexpr (p < SC2.nsp) apply_sp<p>(psiB, umat, tid, x);
    });

    // ---- Measurement directly from last SP's registers
    float e[NW];
    static_for<NW>([&](auto Wc) {
        constexpr int w = (int)decltype(Wc)::value;
        constexpr unsigned pzw = SC2.pz[w];
        float hw = head_w[w];
        e[w] = (__popc(tid & pzw) & 1) ? -hw : hw;
    });
    float c[16];
    static_for<16>([&](auto Mc) { c[decltype(Mc)::value] = 0.f; });
    static_for<NW>([&](auto Wc) {
        constexpr int w = (int)decltype(Wc)::value;
        c[SC2.nib[w]] += e[w];
    });
    static_for<4>([&](auto Bc) {
        constexpr unsigned B = 1u << decltype(Bc)::value;
        static_for<16>([&](auto Kc) {
            constexpr unsigned k = decltype(Kc)::value;
            if constexpr (!(k & B)) {
                float a = c[k], b = c[k | B];
                c[k] = a + b; c[k | B] = a - b;
            }
        });
    });
    float acc = 0.f;
    static_for<16>([&](auto Sc) {
        constexpr int s = (int)decltype(Sc)::value;
        acc += (x[s].x * x[s].x + x[s].y * x[s].y) * c[s];
    });

#pragma unroll
    for (int off = 32; off > 0; off >>= 1)
        acc += __shfl_down(acc, off, 64);
    const unsigned lane = tid & 63, wv = tid >> 6;
    if (lane == 0) red[wv] = acc;
    __syncthreads();
    if (tid == 0) {
        float tot = 0.f;
#pragma unroll
        for (int i = 0; i < TPB / 64; ++i) tot += red[i];
        out[blockIdx.x] = tot + head_b[0];
    }
}

extern "C" void kernel_launch(void* const* d_in, const int* in_sizes, int n_in,
                              void* d_out, int out_size, void* d_ws, size_t ws_size,
                              hipStream_t stream) {
    const float* state  = (const float*)d_in[0];   // (1024, 16384) f32
    const float* params = (const float*)d_in[1];   // (3, 14, 2) f32
    const float* head_w = (const float*)d_in[2];   // (1, 14) f32
    const float* head_b = (const float*)d_in[3];   // (1,) f32
    float* out = (float*)d_out;                    // (1024,) f32

    qsim_kernel<<<out_size, TPB, 0, stream>>>(state, params, head_w, head_b, out);
}

// Round 9
// 133.632 us; speedup vs baseline: 1.1813x; 1.1813x over previous
//
#include <hip/hip_runtime.h>
#include <utility>

#define NW 14
#define NL 3
#define DIM 16384            // 2^14
#define NG  (NL * NW)        // 42 fused RY*RX gates
#define TPB 1024
#define NPH3 11              // 10 phases of 4 gates + 1 phase of 2

typedef float v2f __attribute__((ext_vector_type(2)));

struct S3 {
    int ok = 1;
    unsigned Lane[NPH3][6] = {};   // lane dirs (tid bits 0..5) per phase
    unsigned Reg[NPH3][4]  = {};   // register/slot dirs per phase (gate masks + fillers)
    unsigned Vw[4]         = {};   // global wave dirs (tid bits 6..9)
    unsigned WT[NPH3][6]   = {};   // write consts: coords of lane dirs in NEXT frame
    unsigned WS[NPH3][16]  = {};   // write consts: coords of slot XORs in NEXT frame
    unsigned pv[NPH3][4]   = {};   // runtime sign: 10-bit tid parity mask per gate
    unsigned cp[NPH3][4]   = {};   // compile-time per-slot role bits per gate
    unsigned ST[10] = {}, STK[4] = {}, STJ[4] = {};   // staging coords (phase-0 frame)
    unsigned pz[NW] = {}, nib[NW] = {};               // measurement maps
};

constexpr int rank14(const unsigned* v, int n) {
    unsigned piv[14] = {};
    int r = 0;
    for (int i = 0; i < n; ++i) {
        unsigned x = v[i];
        for (int bit = 13; bit >= 0; --bit) {
            if (!((x >> bit) & 1u)) continue;
            if (piv[bit]) { x ^= piv[bit]; }
            else { piv[bit] = x; ++r; x = 0; break; }
        }
    }
    return r;
}

// coordinates of v in basis bas[14] (bit b of result = coefficient of bas[b])
constexpr unsigned coords14(const unsigned bas[14], unsigned v, int& ok) {
    unsigned pv14[14] = {}, pc14[14] = {};
    for (int b = 0; b < 14; ++b) {
        unsigned x = bas[b], c = 1u << b;
        for (int bit = 13; bit >= 0; --bit) {
            if (!((x >> bit) & 1u)) continue;
            if (pv14[bit]) { x ^= pv14[bit]; c ^= pc14[bit]; }
            else { pv14[bit] = x; pc14[bit] = c; x = 0; break; }
        }
        if (x) ok = 0;
    }
    unsigned x = v, c = 0;
    for (int bit = 13; bit >= 0; --bit) {
        if ((x >> bit) & 1u) {
            if (!pv14[bit]) { ok = 0; return 0; }
            x ^= pv14[bit]; c ^= pc14[bit];
        }
    }
    return c;
}

constexpr S3 build3() {
    S3 S{};
    unsigned mk[NG] = {}, vmg[NG] = {}, zm[NW] = {};
    {   // pair masks (M^-1 columns) and value masks per gate (verified machinery)
        unsigned A[NW] = {};
        for (int w = 0; w < NW; ++w) A[w] = 1u << (NW - 1 - w);
        int g = 0;
        for (int l = 0; l < NL; ++l) {
            unsigned rows[NW] = {};
            for (int u = 0; u < NW; ++u) rows[u] = A[u] | (1u << (NW + u));
            for (int col = 0; col < NW; ++col) {
                int piv = col;
                while (piv < NW && !((rows[piv] >> col) & 1u)) ++piv;
                if (piv >= NW) { S.ok = 0; continue; }
                unsigned tmp = rows[col]; rows[col] = rows[piv]; rows[piv] = tmp;
                for (int r = 0; r < NW; ++r)
                    if (r != col && ((rows[r] >> col) & 1u)) rows[r] ^= rows[col];
            }
            for (int w = 0; w < NW; ++w) {
                unsigned m = 0;
                for (int r = 0; r < NW; ++r) m |= ((rows[r] >> (NW + w)) & 1u) << r;
                mk[g] = m; vmg[g] = A[w]; ++g;
            }
            for (int w = 0; w < NW - 1; ++w) A[w + 1] ^= A[w];  // virtual CNOT chain
            A[0] ^= A[NW - 1];
        }
        for (int w = 0; w < NW; ++w) zm[w] = A[w];
    }
    // slot dirs = gate masks (phases of 4; last phase 2 gates)
    for (int p = 0; p < NPH3; ++p) {
        int J = (p < 10) ? 4 : 2;
        for (int q = 0; q < J; ++q) S.Reg[p][q] = mk[4 * p + q];
    }
    // global wave dirs: 4-dim subspace independent of every group's mask span.
    // NOTE: must search ARBITRARY masks — unit vectors all lie inside layer-0
    // group spans (layer-0 masks are units), so a unit quadruple cannot work.
    {
        int found = 0;
        for (unsigned seed = 1; seed < 256u && !found; ++seed) {
            unsigned cand[4] = {};
            for (int i = 0; i < 4; ++i) {
                unsigned h = (seed * 2654435761u) ^ ((unsigned)(i + 1) * 0x9E3779B9u);
                h ^= h >> 15; h *= 2246822519u; h ^= h >> 13; h *= 3266489917u; h ^= h >> 16;
                cand[i] = h & 0x3FFFu;
            }
            if (rank14(cand, 4) != 4) continue;
            int good = 1;
            for (int g = 0; g < 6 && good; ++g) {
                int nm = (g < 5) ? 8 : 2;
                unsigned set[12] = {}; int n = 0;
                for (int i = 0; i < nm; ++i) set[n++] = mk[8 * g + i];
                for (int i = 0; i < 4; ++i) set[n++] = cand[i];
                if (rank14(set, n) != n) good = 0;
            }
            if (good) { for (int i = 0; i < 4; ++i) S.Vw[i] = cand[i]; found = 1; }
        }
        if (!found) S.ok = 0;
    }
    // per group: fillers and raw lane dirs
    for (int g = 0; g < 6; ++g) {
        int nm = (g < 5) ? 8 : 2;
        unsigned bas[14] = {}; int nb = 0;
        for (int i = 0; i < 4; ++i) bas[nb++] = S.Vw[i];
        for (int i = 0; i < nm; ++i) bas[nb++] = mk[8 * g + i];
        unsigned fill[12] = {}; int nf = 0;
        for (int b = 0; b < 14 && nb < 14; ++b) {
            unsigned t[15] = {};
            for (int i = 0; i < nb; ++i) t[i] = bas[i];
            t[nb] = 1u << b;
            if (rank14(t, nb + 1) == nb + 1) { bas[nb++] = 1u << b; fill[nf++] = 1u << b; }
        }
        if (nb != 14) S.ok = 0;
        if (g < 5) {
            int pA = 2 * g, pB = 2 * g + 1;
            for (int b = 0; b < 4; ++b) { S.Lane[pA][b] = S.Reg[pB][b]; S.Lane[pB][b] = S.Reg[pA][b]; }
            S.Lane[pA][4] = fill[0]; S.Lane[pA][5] = fill[1];
            S.Lane[pB][4] = fill[0]; S.Lane[pB][5] = fill[1];
        } else {
            S.Reg[10][2] = fill[0]; S.Reg[10][3] = fill[1];
            for (int b = 0; b < 6; ++b) S.Lane[10][b] = fill[2 + b];
        }
    }
    // transitions in reverse (reader layouts finalized before writer processed)
    for (int t = NPH3 - 2; t >= 0; --t) {
        unsigned bas[14] = {};
        for (int b = 0; b < 6; ++b) bas[b] = S.Lane[t + 1][b];
        for (int q = 0; q < 4; ++q) bas[6 + q] = S.Reg[t + 1][q];
        for (int j = 0; j < 4; ++j) bas[10 + j] = S.Vw[j];
        // lane corrections (span of writer reg dirs) -> rank-4 bank spread on writes
        unsigned rb[4] = {}; int rn = 0;
        for (int b = 0; b < 6; ++b) {
            int bestcs = 0, bestg = -1; unsigned bestr = 0;
            for (int cs = 0; cs < 16; ++cs) {
                unsigned c = 0;
                for (int q = 0; q < 4; ++q) if ((cs >> q) & 1) c ^= S.Reg[t][q];
                int ok2 = 1;
                unsigned r = coords14(bas, S.Lane[t][b] ^ c, ok2) & 15u;
                if (!ok2) continue;
                unsigned x = r;
                for (int i = 0; i < rn; ++i) {
                    int hb = 3; while (hb > 0 && !((rb[i] >> hb) & 1u)) --hb;
                    if ((x >> hb) & 1u) x ^= rb[i];
                }
                int gain = x ? 1 : 0;
                if (gain > bestg) { bestg = gain; bestcs = cs; bestr = r; }
                if (gain == 1) break;
            }
            unsigned c = 0;
            for (int q = 0; q < 4; ++q) if ((bestcs >> q) & 1) c ^= S.Reg[t][q];
            S.Lane[t][b] ^= c;
            unsigned x = bestr;
            for (int i = 0; i < rn; ++i) {
                int hb = 3; while (hb > 0 && !((rb[i] >> hb) & 1u)) --hb;
                if ((x >> hb) & 1u) x ^= rb[i];
            }
            if (x && rn < 4) rb[rn++] = x;
        }
        int okc = 1;
        for (int b = 0; b < 6; ++b) S.WT[t][b] = coords14(bas, S.Lane[t][b], okc);
        for (int s = 0; s < 16; ++s) {
            unsigned v = 0;
            for (int q = 0; q < 4; ++q) if ((s >> q) & 1) v ^= S.Reg[t][q];
            S.WS[t][s] = coords14(bas, v, okc);
        }
        if (!okc) S.ok = 0;
        if ((t & 1) == 0) {   // in-group transition must be wave-local
            for (int b = 0; b < 6; ++b) if (S.WT[t][b] >> 10) S.ok = 0;
            for (int s = 0; s < 16; ++s) if (S.WS[t][s] >> 10) S.ok = 0;
        }
        // verify: reader-amp(writer-idx) == writer-amp on basis inputs
        for (int ub = 0; ub < 10; ++ub) {
            unsigned wamp = (ub < 6) ? S.Lane[t][ub] : S.Vw[ub - 6];
            unsigned widx = (ub < 6) ? S.WT[t][ub] : (1u << (10 + ub - 6));
            unsigned ramp = 0;
            for (int b = 0; b < 6; ++b) if ((widx >> b) & 1u) ramp ^= S.Lane[t + 1][b];
            for (int q = 0; q < 4; ++q) if ((widx >> (6 + q)) & 1u) ramp ^= S.Reg[t + 1][q];
            for (int j = 0; j < 4; ++j) if ((widx >> (10 + j)) & 1u) ramp ^= S.Vw[j];
            if (ramp != wamp) S.ok = 0;
        }
        for (int q = 0; q < 4; ++q) {
            unsigned widx = S.WS[t][1u << q];
            unsigned ramp = 0;
            for (int b = 0; b < 6; ++b) if ((widx >> b) & 1u) ramp ^= S.Lane[t + 1][b];
            for (int qq = 0; qq < 4; ++qq) if ((widx >> (6 + qq)) & 1u) ramp ^= S.Reg[t + 1][qq];
            for (int j = 0; j < 4; ++j) if ((widx >> (10 + j)) & 1u) ramp ^= S.Vw[j];
            if (ramp != S.Reg[t][q]) S.ok = 0;
        }
    }
    // signs (final dirs)
    for (int p = 0; p < NPH3; ++p) {
        int J = (p < 10) ? 4 : 2;
        for (int q = 0; q < J; ++q) {
            unsigned vm = vmg[4 * p + q], pvm = 0;
            for (int b = 0; b < 6; ++b)
                if (__builtin_popcount(S.Lane[p][b] & vm) & 1) pvm |= 1u << b;
            for (int j = 0; j < 4; ++j)
                if (__builtin_popcount(S.Vw[j] & vm) & 1) pvm |= 1u << (6 + j);
            S.pv[p][q] = pvm;
            unsigned cpm = 0;
            for (int s = 0; s < 16; ++s) {
                unsigned v = 0;
                for (int q2 = 0; q2 < 4; ++q2) if ((s >> q2) & 1) v ^= S.Reg[p][q2];
                if (__builtin_popcount(v & vm) & 1) cpm |= 1u << s;
            }
            S.cp[p][q] = cpm;
        }
    }
    // staging coords (reader = phase 0) + verification
    {
        unsigned bas[14] = {};
        for (int b = 0; b < 6; ++b) bas[b] = S.Lane[0][b];
        for (int q = 0; q < 4; ++q) bas[6 + q] = S.Reg[0][q];
        for (int j = 0; j < 4; ++j) bas[10 + j] = S.Vw[j];
        int okc = 1;
        for (int b = 0; b < 10; ++b) S.ST[b] = coords14(bas, 1u << (b + 2), okc);
        for (int k = 0; k < 4; ++k) S.STK[k] = coords14(bas, (unsigned)k << 12, okc);
        for (int j = 0; j < 4; ++j) S.STJ[j] = coords14(bas, (unsigned)j, okc);
        if (!okc) S.ok = 0;
        for (int ub = 0; ub < 18; ++ub) {
            unsigned amp = (ub < 10) ? (1u << (ub + 2))
                         : (ub < 14) ? ((unsigned)(ub - 10) << 12) : (unsigned)(ub - 14);
            unsigned widx = (ub < 10) ? S.ST[ub] : (ub < 14) ? S.STK[ub - 10] : S.STJ[ub - 14];
            unsigned ramp = 0;
            for (int b = 0; b < 6; ++b) if ((widx >> b) & 1u) ramp ^= S.Lane[0][b];
            for (int q = 0; q < 4; ++q) if ((widx >> (6 + q)) & 1u) ramp ^= S.Reg[0][q];
            for (int j = 0; j < 4; ++j) if ((widx >> (10 + j)) & 1u) ramp ^= S.Vw[j];
            if (ramp != amp) S.ok = 0;
        }
    }
    // measurement from phase-10 registers
    for (int w = 0; w < NW; ++w) {
        unsigned pzm = 0;
        for (int b = 0; b < 6; ++b)
            if (__builtin_popcount(S.Lane[10][b] & zm[w]) & 1) pzm |= 1u << b;
        for (int j = 0; j < 4; ++j)
            if (__builtin_popcount(S.Vw[j] & zm[w]) & 1) pzm |= 1u << (6 + j);
        S.pz[w] = pzm;
        unsigned nv = 0;
        for (int q = 0; q < 4; ++q)
            if (__builtin_popcount(S.Reg[10][q] & zm[w]) & 1) nv |= 1u << q;
        S.nib[w] = nv;
    }
    return S;
}
constexpr S3 SC3 = build3();
static_assert(SC3.ok == 1, "schedule build failed");

// ---------------- static_for ----------------
template<class F, unsigned... I>
__device__ __forceinline__ void static_for_impl(F&& f, std::integer_sequence<unsigned, I...>) {
    (f(std::integral_constant<unsigned, I>{}), ...);
}
template<unsigned N, class F>
__device__ __forceinline__ void static_for(F&& f) {
    static_for_impl(static_cast<F&&>(f), std::make_integer_sequence<unsigned, N>{});
}

// ---------------- packed complex mul/mac (verified r4/r6/r7) ----------------
template<int NEGLO, int NEGHI>
__device__ __forceinline__ v2f cmul(v2f k, v2f x) {
    v2f y;
    if constexpr (!NEGLO)
        asm("v_pk_mul_f32 %0, %1, %2 op_sel:[0,0] op_sel_hi:[0,1]"
            : "=&v"(y) : "v"(k), "v"(x));
    else
        asm("v_pk_mul_f32 %0, %1, %2 op_sel:[0,0] op_sel_hi:[0,1] neg_lo:[1,0] neg_hi:[1,0]"
            : "=&v"(y) : "v"(k), "v"(x));
    if constexpr (!NEGHI)
        asm("v_pk_fma_f32 %0, %1, %2, %0 op_sel:[1,1,0] op_sel_hi:[1,0,1] neg_lo:[0,1,0]"
            : "+v"(y) : "v"(k), "v"(x));
    else
        asm("v_pk_fma_f32 %0, %1, %2, %0 op_sel:[1,1,0] op_sel_hi:[1,0,1] neg_lo:[1,1,0] neg_hi:[1,0,0]"
            : "+v"(y) : "v"(k), "v"(x));
    return y;
}
template<int NEGLO, int NEGHI>
__device__ __forceinline__ void cmac(v2f& y, v2f k, v2f x) {
    if constexpr (!NEGLO)
        asm("v_pk_fma_f32 %0, %1, %2, %0 op_sel:[0,0,0] op_sel_hi:[0,1,1]"
            : "+v"(y) : "v"(k), "v"(x));
    else
        asm("v_pk_fma_f32 %0, %1, %2, %0 op_sel:[0,0,0] op_sel_hi:[0,1,1] neg_lo:[1,0,0] neg_hi:[1,0,0]"
            : "+v"(y) : "v"(k), "v"(x));
    if constexpr (!NEGHI)
        asm("v_pk_fma_f32 %0, %1, %2, %0 op_sel:[1,1,0] op_sel_hi:[1,0,1] neg_lo:[0,1,0]"
            : "+v"(y) : "v"(k), "v"(x));
    else
        asm("v_pk_fma_f32 %0, %1, %2, %0 op_sel:[1,1,0] op_sel_hi:[1,0,1] neg_lo:[1,1,0] neg_hi:[1,0,0]"
            : "+v"(y) : "v"(k), "v"(x));
}
template<bool CS> __device__ __forceinline__ v2f  cmulA(v2f k, v2f x) { return cmul<0, CS ? 1 : 0>(k, x); }
template<bool CS> __device__ __forceinline__ void cmacB(v2f& y, v2f k, v2f x) { cmac<CS ? 1 : 0, 0>(y, k, x); }

__global__ __launch_bounds__(TPB) void qsim_kernel(
    const float* __restrict__ state,
    const float* __restrict__ params,
    const float* __restrict__ head_w,
    const float* __restrict__ head_b,
    float* __restrict__ out)
{
    __shared__ v2f    psi[DIM];          // 128 KB: 16 wave-regions x 8 KB
    __shared__ float4 umat[NG];
    __shared__ float  red[TPB / 64];
    char* psiB = (char*)psi;
    const unsigned tid = threadIdx.x;

    // Fused U = RY(t2)*RX(t1) = [[a,b],[-conj(b),conj(a)]]; a=(c1c2,s1s2), b=(-s2c1,-c2s1)
    if (tid < NG) {
        float t1 = 0.5f * params[2 * tid + 0];
        float t2 = 0.5f * params[2 * tid + 1];
        float s1, c1, s2, c2;
        sincosf(t1, &s1, &c1);
        sincosf(t2, &s2, &c2);
        umat[tid] = make_float4(c1 * c2, s1 * s2, -s2 * c1, -c2 * s1);
    }

    // Staging: coalesced float4 read -> phase-0 frame coords (imag = 0)
    unsigned sidx = 0;
    static_for<10>([&](auto Bc) {
        constexpr int b = (int)decltype(Bc)::value;
        sidx ^= SC3.ST[b] & (unsigned)(-(int)((tid >> b) & 1u));
    });
    const float4* st4 = reinterpret_cast<const float4*>(state) + (size_t)blockIdx.x * (DIM / 4);
    static_for<4>([&](auto Kc) {
        constexpr int k = (int)decltype(Kc)::value;
        float4 v = st4[tid + k * TPB];
        const unsigned bi = sidx ^ SC3.STK[k];
        *(v2f*)(psiB + ((bi ^ SC3.STJ[0]) << 3)) = (v2f){ v.x, 0.f };
        *(v2f*)(psiB + ((bi ^ SC3.STJ[1]) << 3)) = (v2f){ v.y, 0.f };
        *(v2f*)(psiB + ((bi ^ SC3.STJ[2]) << 3)) = (v2f){ v.z, 0.f };
        *(v2f*)(psiB + ((bi ^ SC3.STJ[3]) << 3)) = (v2f){ v.w, 0.f };
    });
    __syncthreads();

    // frame layout: byte = [wave(tid6..9) <<13 | slot <<9 | lane(tid0..5) <<3]
    const unsigned rbase = ((tid >> 6) << 13) | ((tid & 63u) << 3);
    v2f x[16];

    static_for<NPH3>([&](auto Pc) {
        constexpr int P = (int)decltype(Pc)::value;
        // contiguous conflict-free reads: one base + immediate offsets
        static_for<16>([&](auto Sc) {
            constexpr int s = (int)decltype(Sc)::value;
            x[s] = *(const v2f*)(psiB + rbase + (s << 9));
        });
        // gates (all in registers)
        static_for<4>([&](auto Qc) {
            constexpr int q = (int)decltype(Qc)::value;
            if constexpr (q < ((P < 10) ? 4 : 2)) {
                constexpr unsigned cp  = SC3.cp[P][q];
                constexpr unsigned pvm = SC3.pv[P][q];
                const float4 u = umat[4 * P + q];
                const unsigned sm = ((unsigned)__popc(tid & pvm)) << 31;
                v2f A, B;  // A = (ar, ai^s), B = (br^s, bi)
                A.x = u.x; A.y = __uint_as_float(__float_as_uint(u.y) ^ sm);
                B.x = __uint_as_float(__float_as_uint(u.z) ^ sm); B.y = u.w;
                static_for<8>([&](auto Pp) {
                    constexpr unsigned pp   = decltype(Pp)::value;
                    constexpr unsigned lowm = (1u << q) - 1u;
                    constexpr unsigned s0   = ((pp & ~lowm) << 1) | (pp & lowm);
                    constexpr unsigned s1   = s0 | (1u << q);
                    constexpr bool c0 = (cp >> s0) & 1u;
                    constexpr bool c1 = (cp >> s1) & 1u;
                    const v2f x0 = x[s0], x1 = x[s1];
                    v2f y0 = cmulA<c0>(A, x0); cmacB<c0>(y0, B, x1);
                    v2f y1 = cmulA<c1>(A, x1); cmacB<c1>(y1, B, x0);
                    x[s0] = y0; x[s1] = y1;
                });
            }
        });
        // write to next frame
        if constexpr (P < 10) {
            if constexpr (P & 1) __syncthreads();   // boundary: all reads done
            unsigned wi = (tid >> 6) << 10;
            static_for<6>([&](auto Bc) {
                constexpr int b = (int)decltype(Bc)::value;
                wi ^= SC3.WT[P][b] & (unsigned)(-(int)((tid >> b) & 1u));
            });
            static_for<16>([&](auto Sc) {
                constexpr int s = (int)decltype(Sc)::value;
                *(v2f*)(psiB + ((wi ^ SC3.WS[P][s]) << 3)) = x[s];
            });
            if constexpr (P & 1) __syncthreads();   // boundary: frame visible
            // even P: wave-local exchange, no barrier needed
        }
    });

    // Measurement directly from phase-10 registers
    float e[NW];
    static_for<NW>([&](auto Wc) {
        constexpr int w = (int)decltype(Wc)::value;
        constexpr unsigned pzw = SC3.pz[w];
        float hw = head_w[w];
        e[w] = (__popc(tid & pzw) & 1) ? -hw : hw;
    });
    float c[16];
    static_for<16>([&](auto Mc) { c[decltype(Mc)::value] = 0.f; });
    static_for<NW>([&](auto Wc) {
        constexpr int w = (int)decltype(Wc)::value;
        c[SC3.nib[w]] += e[w];
    });
    static_for<4>([&](auto Bc) {
        constexpr unsigned B = 1u << decltype(Bc)::value;
        static_for<16>([&](auto Kc) {
            constexpr unsigned k = decltype(Kc)::value;
            if constexpr (!(k & B)) {
                float a = c[k], b = c[k | B];
                c[k] = a + b; c[k | B] = a - b;
            }
        });
    });
    float acc = 0.f;
    static_for<16>([&](auto Sc) {
        constexpr int s = (int)decltype(Sc)::value;
        acc += (x[s].x * x[s].x + x[s].y * x[s].y) * c[s];
    });

#pragma unroll
    for (int off = 32; off > 0; off >>= 1)
        acc += __shfl_down(acc, off, 64);
    const unsigned lane = tid & 63, wv = tid >> 6;
    if (lane == 0) red[wv] = acc;
    __syncthreads();
    if (tid == 0) {
        float tot = 0.f;
#pragma unroll
        for (int i = 0; i < TPB / 64; ++i) tot += red[i];
        out[blockIdx.x] = tot + head_b[0];
    }
}

extern "C" void kernel_launch(void* const* d_in, const int* in_sizes, int n_in,
                              void* d_out, int out_size, void* d_ws, size_t ws_size,
                              hipStream_t stream) {
    const float* state  = (const float*)d_in[0];   // (1024, 16384) f32
    const float* params = (const float*)d_in[1];   // (3, 14, 2) f32
    const float* head_w = (const float*)d_in[2];   // (1, 14) f32
    const float* head_b = (const float*)d_in[3];   // (1,) f32
    float* out = (float*)d_out;                    // (1024,) f32

    qsim_kernel<<<out_size, TPB, 0, stream>>>(state, params, head_w, head_b, out);
}